// Round 10
// baseline (837.365 us; speedup 1.0000x reference)
//
#include <hip/hip_runtime.h>
#include <hip/hip_bf16.h>
#include <stdint.h>

typedef unsigned short u16;

#define B_ 8
#define S_ 2048
#define Q_ 2048
#define D_ 1024
#define T_ 2048

typedef __attribute__((ext_vector_type(8))) short short8;
typedef __attribute__((ext_vector_type(16))) float f32x16;

__device__ __forceinline__ u16 f2b(float f) {
  union { float f; uint32_t u; } x; x.f = f;
  uint32_t r = x.u + 0x7fffu + ((x.u >> 16) & 1u);
  return (u16)(r >> 16);
}
__device__ __forceinline__ float b2f(u16 h) {
  union { uint32_t u; float f; } x; x.u = ((uint32_t)h) << 16;
  return x.f;
}
__device__ __forceinline__ float tanh_fast(float x) {
  return 1.0f - 2.0f / (__expf(2.0f * x) + 1.0f);
}
__device__ __forceinline__ void async16(const void* g, void* l) {
  __builtin_amdgcn_global_load_lds(
      (const __attribute__((address_space(1))) void*)g,
      (__attribute__((address_space(3))) void*)l, 16, 0, 0);
}

// ---------------- elementwise cast f32 -> bf16 (4 elems/thread) ----------------
__global__ void cast_f32_bf16_k(const float* __restrict__ in, u16* __restrict__ out, int n4) {
  int i = blockIdx.x * 256 + threadIdx.x;
  if (i >= n4) return;
  float4 v = ((const float4*)in)[i];
  uint32_t lo = (uint32_t)f2b(v.x) | ((uint32_t)f2b(v.y) << 16);
  uint32_t hi = (uint32_t)f2b(v.z) | ((uint32_t)f2b(v.w) << 16);
  ((uint2*)out)[i] = make_uint2(lo, hi);
}

// ------- tiled transpose f32 (z,R,C) -> bf16 (z,C,R); 64x64 tile, vector IO -------
__global__ void transpose_f32_bf16_v(const float* __restrict__ in, u16* __restrict__ out,
                                     int R, int C) {
  __shared__ u16 t[64 * 72];
  int z = blockIdx.z;
  const float* pin = in + (size_t)z * R * C;
  u16* pout = out + (size_t)z * R * C;
  int c0 = blockIdx.x * 64, r0 = blockIdx.y * 64;
  int tid = threadIdx.x;
  int rr = tid >> 4, c4 = (tid & 15) * 4;
#pragma unroll
  for (int p = 0; p < 4; ++p) {
    int r = p * 16 + rr;
    float4 v = *(const float4*)&pin[(size_t)(r0 + r) * C + c0 + c4];
    t[(c4 + 0) * 72 + r] = f2b(v.x);
    t[(c4 + 1) * 72 + r] = f2b(v.y);
    t[(c4 + 2) * 72 + r] = f2b(v.z);
    t[(c4 + 3) * 72 + r] = f2b(v.w);
  }
  __syncthreads();
  int ct = tid >> 3, r8 = (tid & 7) * 8;
#pragma unroll
  for (int p = 0; p < 2; ++p) {
    int c = p * 32 + ct;
    uint2 lo = *(const uint2*)&t[c * 72 + r8];
    uint2 hi = *(const uint2*)&t[c * 72 + r8 + 4];
    *(uint4*)&pout[(size_t)(c0 + c) * R + r0 + r8] = make_uint4(lo.x, lo.y, hi.x, hi.y);
  }
}

// --- src prep: f32 (b,S,D) -> bf16 copy (b,S,D) + bf16 transpose (b,D,S); vector IO ---
__global__ void src_prep_v(const float* __restrict__ in, u16* __restrict__ outc,
                           u16* __restrict__ outT) {
  __shared__ u16 t[64 * 72];
  int z = blockIdx.z;
  const float* pin = in + (size_t)z * S_ * D_;
  u16* pc = outc + (size_t)z * S_ * D_;
  u16* pt = outT + (size_t)z * S_ * D_;
  int c0 = blockIdx.x * 64, r0 = blockIdx.y * 64;  // r over S, c over D
  int tid = threadIdx.x;
  int rr = tid >> 4, c4 = (tid & 15) * 4;
#pragma unroll
  for (int p = 0; p < 4; ++p) {
    int r = p * 16 + rr;
    float4 v = *(const float4*)&pin[(size_t)(r0 + r) * D_ + c0 + c4];
    u16 b0 = f2b(v.x), b1 = f2b(v.y), b2 = f2b(v.z), b3 = f2b(v.w);
    uint2 pk;
    pk.x = (uint32_t)b0 | ((uint32_t)b1 << 16);
    pk.y = (uint32_t)b2 | ((uint32_t)b3 << 16);
    *(uint2*)&pc[(size_t)(r0 + r) * D_ + c0 + c4] = pk;
    t[(c4 + 0) * 72 + r] = b0;
    t[(c4 + 1) * 72 + r] = b1;
    t[(c4 + 2) * 72 + r] = b2;
    t[(c4 + 3) * 72 + r] = b3;
  }
  __syncthreads();
  int ct = tid >> 3, r8 = (tid & 7) * 8;
#pragma unroll
  for (int p = 0; p < 2; ++p) {
    int c = p * 32 + ct;
    uint2 lo = *(const uint2*)&t[c * 72 + r8];
    uint2 hi = *(const uint2*)&t[c * 72 + r8 + 4];
    *(uint4*)&pt[(size_t)(c0 + c) * S_ + r0 + r8] = make_uint4(lo.x, lo.y, hi.x, hi.y);
  }
}

// ------- scale srcT (b,d,s) in place by 1/l[b*S+s]; 8 elems/thread -------
__global__ void scale_srcT_k(u16* __restrict__ srcT, const float* __restrict__ l) {
  size_t i = (size_t)blockIdx.x * 256 + threadIdx.x;  // group of 8 u16
  size_t e0 = i * 8;
  int s8 = (int)(e0 & (S_ - 1));
  int bb = (int)(e0 / ((size_t)D_ * S_));
  const float* lp = l + (size_t)bb * S_ + s8;
  float4 l0 = *(const float4*)lp;
  float4 l1 = *(const float4*)(lp + 4);
  uint4 raw = *(uint4*)&srcT[e0];
  uint32_t w[4] = {raw.x, raw.y, raw.z, raw.w};
  float li[8] = {l0.x, l0.y, l0.z, l0.w, l1.x, l1.y, l1.z, l1.w};
  uint32_t o[4];
#pragma unroll
  for (int k = 0; k < 4; ++k) {
    float a = b2f((u16)(w[k] & 0xffffu)) / li[2 * k];
    float b = b2f((u16)(w[k] >> 16)) / li[2 * k + 1];
    o[k] = (uint32_t)f2b(a) | ((uint32_t)f2b(b) << 16);
  }
  *(uint4*)&srcT[e0] = make_uint4(o[0], o[1], o[2], o[3]);
}

// =====================================================================
// R10 = R0 baseline (128x128 tile, 2-barrier m97 loop, 4 blocks/CU TLP,
// 818 TF measured here; m97/m103 = 874-912 on this chip) + this
// session's ONE verified lever: FRAGMENT-CONTIGUOUS LDS (R6: conflicts
// 1.5e7 -> 5.2e5). R0 carried 1.73e7 conflict-cycles ≈ 17% of dispatch.
// Diff vs R0 is ONLY the LDS layout + staging/read addressing:
//  - per operand tile (128 rows x 64 k): 16 blocks of 1 KB indexed
//    (s,kk), s = 32-row group (0..3), kk = 16-k slice (0..3). Block
//    holds lane l's 16-B MFMA fragment at base + l*16 B:
//    elem [s*32 + (l&31)][kt + kk*16 + (l>>5)*8 .. +7]   (32x32 frag).
//  - DMA dest linear per block (wave-uniform base + lane*16 legal);
//    the GLOBAL source does the fragment gather (R7 validated this
//    exact gather: correct + FETCH-neutral).
//  - every ds_read_b128 is const + lane*16B: conflict-free by
//    construction (2 lanes/bank pairing is free, m136).
// Rationale: at 4 blocks/CU the HW already overlaps pipes across
// blocks (m114); R1-R9 proved 1-block/CU 256² cannot be made to
// overlap at source level (584 us plateau, 3 falsified schedules).
// modes: 0 tanh->bf16, 1 ->bf16, 2 ->f32, 3 exp + rowsum + P^T bf16.
// =====================================================================
__global__ __launch_bounds__(256, 4) void gemm_bt_k(
    const u16* __restrict__ A1, long lda1, long bsA1,
    const u16* __restrict__ B1, long ldb1, long bsB1,
    const u16* __restrict__ A2, long lda2, long bsA2,
    const u16* __restrict__ B2, long ldb2, long bsB2,
    void* __restrict__ Cv, long ldc, long bsC,
    int K, int Srows, int nTerms, int mode, float* __restrict__ lsum) {
  __shared__ __align__(16) u16 lds_all[16896];  // 33792 B; tiles use 32 KB
  u16* lds_a = lds_all;            // A tile: 16 blocks x 512 u16
  u16* lds_b = lds_all + 8192;     // B tile
  const int m0 = blockIdx.y * 128;
  const int n0 = blockIdx.x * 128;
  const int b = m0 / Srows;
  const int s0 = m0 - b * Srows;
  const int tid = threadIdx.x;
  const int wave = tid >> 6, lane = tid & 63;
  const int wm = (wave >> 1) * 64, wn = (wave & 1) * 64;
  const int l31 = lane & 31, hi = lane >> 5;

  // fragment block offsets (u16): block (s,kk) at (s*4 + kk)*512
  const int aS0 = (wave >> 1) * 2;     // A s-blocks for this wave: aS0, aS0+1
  const int bS0 = (wave & 1) * 2;      // B s-blocks
  const int lof = lane * 8;

  f32x16 acc[2][2];
#pragma unroll
  for (int i = 0; i < 2; ++i)
#pragma unroll
    for (int j = 0; j < 2; ++j)
#pragma unroll
      for (int r = 0; r < 16; ++r) acc[i][j][r] = 0.0f;

  const u16* pA[2];
  const u16* pB[2];
  long la[2], lb[2];
  pA[0] = A1 + (size_t)bsA1 * b + (size_t)s0 * lda1;
  pB[0] = B1 + (size_t)bsB1 * b + (size_t)n0 * ldb1;
  pA[1] = (nTerms > 1) ? (A2 + (size_t)bsA2 * b + (size_t)s0 * lda2) : pA[0];
  pB[1] = (nTerms > 1) ? (B2 + (size_t)bsB2 * b + (size_t)n0 * ldb2) : pB[0];
  la[0] = lda1; la[1] = lda2;
  lb[0] = ldb1; lb[1] = ldb2;

  for (int t = 0; t < nTerms; ++t) {
    const u16* gA = pA[t];
    const u16* gB = pB[t];
    const long sA = la[t], sB = lb[t];
    for (int kt = 0; kt < K; kt += 64) {
      // stage: wave w covers kk=w for all 4 s-blocks of A and B.
      // lane l -> row s*32 + (l&31), k = kt + w*16 + (l>>5)*8 (16 B).
#pragma unroll
      for (int j = 0; j < 4; ++j) {
        async16(gA + (size_t)(j * 32 + l31) * sA + (kt + wave * 16 + hi * 8),
                &lds_a[(j * 4 + wave) * 512]);
        async16(gB + (size_t)(j * 32 + l31) * sB + (kt + wave * 16 + hi * 8),
                &lds_b[(j * 4 + wave) * 512]);
      }
      __syncthreads();  // drains vmcnt: all 32 KB landed
#pragma unroll
      for (int kk = 0; kk < 4; ++kk) {
        short8 a0 = *(const short8*)&lds_a[((aS0 + 0) * 4 + kk) * 512 + lof];
        short8 a1 = *(const short8*)&lds_a[((aS0 + 1) * 4 + kk) * 512 + lof];
        short8 b0 = *(const short8*)&lds_b[((bS0 + 0) * 4 + kk) * 512 + lof];
        short8 b1 = *(const short8*)&lds_b[((bS0 + 1) * 4 + kk) * 512 + lof];
        acc[0][0] = __builtin_amdgcn_mfma_f32_32x32x16_bf16(a0, b0, acc[0][0], 0, 0, 0);
        acc[0][1] = __builtin_amdgcn_mfma_f32_32x32x16_bf16(a0, b1, acc[0][1], 0, 0, 0);
        acc[1][0] = __builtin_amdgcn_mfma_f32_32x32x16_bf16(a1, b0, acc[1][0], 0, 0, 0);
        acc[1][1] = __builtin_amdgcn_mfma_f32_32x32x16_bf16(a1, b1, acc[1][1], 0, 0, 0);
      }
      __syncthreads();  // all reads drained before next stage overwrites
    }
  }

  // C/D layout (32x32): col = lane&31, row = (reg&3) + 8*(reg>>2) + 4*(lane>>5)
  if (mode == 3) {
    // 1) in-place exp
#pragma unroll
    for (int mi = 0; mi < 2; ++mi)
#pragma unroll
      for (int ni = 0; ni < 2; ++ni)
#pragma unroll
        for (int r = 0; r < 16; ++r)
          acc[mi][ni][r] = __expf(acc[mi][ni][r]);
    // 2) row sums over this block's 128 cols -> atomicAdd lsum
    float* lrow = lsum + (size_t)b * Srows + s0;
#pragma unroll
    for (int mi = 0; mi < 2; ++mi)
#pragma unroll
      for (int r = 0; r < 16; ++r) {
        float pv = acc[mi][0][r] + acc[mi][1][r];
        pv += __shfl_xor(pv, 1);
        pv += __shfl_xor(pv, 2);
        pv += __shfl_xor(pv, 4);
        pv += __shfl_xor(pv, 8);
        pv += __shfl_xor(pv, 16);
        const int row = wm + mi * 32 + (r & 3) + 8 * (r >> 2) + 4 * hi;
        if (l31 == 0) atomicAdd(&lrow[row], pv);
      }
    // 3) transpose via LDS tile [t][s], u16 stride 132
#pragma unroll
    for (int mi = 0; mi < 2; ++mi)
#pragma unroll
      for (int ni = 0; ni < 2; ++ni) {
        const int col = wn + ni * 32 + l31;  // t index
#pragma unroll
        for (int g = 0; g < 4; ++g) {
          const int rowb = wm + mi * 32 + g * 8 + 4 * hi;  // 4 consecutive s
          u16 p0 = f2b(acc[mi][ni][g * 4 + 0]);
          u16 p1 = f2b(acc[mi][ni][g * 4 + 1]);
          u16 p2 = f2b(acc[mi][ni][g * 4 + 2]);
          u16 p3 = f2b(acc[mi][ni][g * 4 + 3]);
          uint2 pk;
          pk.x = (uint32_t)p0 | ((uint32_t)p1 << 16);
          pk.y = (uint32_t)p2 | ((uint32_t)p3 << 16);
          *(uint2*)&lds_all[col * 132 + rowb] = pk;
        }
      }
    __syncthreads();
    // 4) coalesced transposed write: P^T[b, n0+t, s0+s]
    u16* gP = (u16*)Cv + (size_t)bsC * b + (size_t)n0 * ldc + s0;
    const int tl = tid >> 4, s8 = (tid & 15) * 8;
#pragma unroll
    for (int p = 0; p < 8; ++p) {
      const int tt = p * 16 + tl;
      uint2 lo = *(const uint2*)&lds_all[tt * 132 + s8];
      uint2 hi2 = *(const uint2*)&lds_all[tt * 132 + s8 + 4];
      *(uint4*)&gP[(size_t)tt * ldc + s8] = make_uint4(lo.x, lo.y, hi2.x, hi2.y);
    }
    return;
  }

  const size_t cbase = (size_t)bsC * b + (size_t)s0 * ldc + n0;
  if (mode == 2) {
    float* C = (float*)Cv + cbase;
#pragma unroll
    for (int mi = 0; mi < 2; ++mi)
#pragma unroll
      for (int ni = 0; ni < 2; ++ni) {
        const int col = wn + ni * 32 + l31;
#pragma unroll
        for (int r = 0; r < 16; ++r) {
          const int row = wm + mi * 32 + (r & 3) + 8 * (r >> 2) + 4 * hi;
          C[(size_t)row * ldc + col] = acc[mi][ni][r];
        }
      }
  } else {
    u16* C = (u16*)Cv + cbase;
#pragma unroll
    for (int mi = 0; mi < 2; ++mi)
#pragma unroll
      for (int ni = 0; ni < 2; ++ni) {
        const int col = wn + ni * 32 + l31;
#pragma unroll
        for (int r = 0; r < 16; ++r) {
          const int row = wm + mi * 32 + (r & 3) + 8 * (r >> 2) + 4 * hi;
          float v = acc[mi][ni][r];
          if (mode == 0) v = tanh_fast(v);
          C[(size_t)row * ldc + col] = f2b(v);
        }
      }
  }
}

extern "C" void kernel_launch(void* const* d_in, const int* in_sizes, int n_in,
                              void* d_out, int out_size, void* d_ws, size_t ws_size,
                              hipStream_t stream) {
  const float* src = (const float*)d_in[0];  // (B,S,D)
  const float* qry = (const float*)d_in[1];  // (B,Q,D)
  const float* ker = (const float*)d_in[2];  // (Q,T)
  const float* wk  = (const float*)d_in[3];  // (D,Q)
  const float* wq  = (const float*)d_in[4];  // (S,D)
  float* out = (float*)d_out;                // (B,T,D)
  u16* ws = (u16*)d_ws;

  // workspace layout (halfwords); ~240 MB
  u16* srcb  = ws;                                // (B,S,D) bf16
  u16* qryb  = srcb  + (size_t)B_ * S_ * D_;      // (B,Q,D) bf16
  u16* wqb   = qryb  + (size_t)B_ * Q_ * D_;      // (S,D) bf16
  u16* wkT   = wqb   + (size_t)S_ * D_;           // (Q,D) bf16
  u16* kerT  = wkT   + (size_t)D_ * Q_;           // (T,Q) bf16
  u16* srcT  = kerT  + (size_t)Q_ * T_;           // (B,D,S) bf16; scaled in place by 1/l
  u16* tanhT = srcT  + (size_t)B_ * D_ * S_;      // (B,S,Q) bf16
  u16* PT    = tanhT + (size_t)B_ * S_ * Q_;      // (B,T,S) bf16 = exp(sim)^T
  float* l   = (float*)(PT + (size_t)B_ * T_ * S_);  // (B*S) row sums

  dim3 tb(256);

  // prep
  cast_f32_bf16_k<<<(B_ * Q_ * D_) / 1024, 256, 0, stream>>>(qry, qryb, (B_ * Q_ * D_) / 4);
  cast_f32_bf16_k<<<(S_ * D_) / 1024, 256, 0, stream>>>(wq, wqb, (S_ * D_) / 4);
  transpose_f32_bf16_v<<<dim3(Q_ / 64, D_ / 64, 1), tb, 0, stream>>>(wk, wkT, D_, Q_);
  transpose_f32_bf16_v<<<dim3(T_ / 64, Q_ / 64, 1), tb, 0, stream>>>(ker, kerT, Q_, T_);
  src_prep_v<<<dim3(D_ / 64, S_ / 64, B_), tb, 0, stream>>>(src, srcb, srcT);
  hipMemsetAsync(l, 0, (size_t)B_ * S_ * sizeof(float), stream);

  // GEMM1: tanh(src@wk + wq@q_t) -> tanhT  (M=B*S, N=Q, K=D, 2 terms)
  gemm_bt_k<<<dim3(Q_ / 128, (B_ * S_) / 128), 256, 0, stream>>>(
      srcb, D_, (long)S_ * D_,
      wkT, D_, 0,
      wqb, D_, 0,
      qryb, D_, (long)Q_ * D_,
      tanhT, Q_, (long)S_ * Q_,
      D_, S_, 2, 0, nullptr);

  // GEMM2: P^T = exp(tanhT @ kernel)^T -> PT (B,T,S); row sums -> l  (M=B*S, N=T, K=Q)
  gemm_bt_k<<<dim3(T_ / 128, (B_ * S_) / 128), 256, 0, stream>>>(
      tanhT, Q_, (long)S_ * Q_,
      kerT, Q_, 0,
      nullptr, 0, 0, nullptr, 0, 0,
      PT, S_, (long)T_ * S_,
      Q_, S_, 1, 3, l);

  // scale srcT by 1/l (in place)
  scale_srcT_k<<<(B_ * D_ * S_) / (256 * 8), 256, 0, stream>>>(srcT, l);

  // GEMM3: out[b] = PT[b] @ srcT_scaled[b]  (M=B*T, N=D, K=S), fp32 epilogue
  gemm_bt_k<<<dim3(D_ / 128, (B_ * T_) / 128), 256, 0, stream>>>(
      PT, S_, (long)T_ * S_,
      srcT, S_, (long)D_ * S_,
      nullptr, 0, 0, nullptr, 0, 0,
      out, D_, (long)T_ * D_,
      S_, T_, 1, 2, nullptr);
}

// Round 11
// 577.333 us; speedup vs baseline: 1.4504x; 1.4504x over previous
//
#include <hip/hip_runtime.h>
#include <hip/hip_bf16.h>
#include <stdint.h>

typedef unsigned short u16;

#define B_ 8
#define S_ 2048
#define Q_ 2048
#define D_ 1024
#define T_ 2048

typedef __attribute__((ext_vector_type(8))) short short8;
typedef __attribute__((ext_vector_type(4))) float f32x4;

__device__ __forceinline__ u16 f2b(float f) {
  union { float f; uint32_t u; } x; x.f = f;
  uint32_t r = x.u + 0x7fffu + ((x.u >> 16) & 1u);
  return (u16)(r >> 16);
}
__device__ __forceinline__ float b2f(u16 h) {
  union { uint32_t u; float f; } x; x.u = ((uint32_t)h) << 16;
  return x.f;
}
__device__ __forceinline__ float tanh_fast(float x) {
  return 1.0f - 2.0f / (__expf(2.0f * x) + 1.0f);
}
__device__ __forceinline__ void async16(const void* g, void* l) {
  __builtin_amdgcn_global_load_lds(
      (const __attribute__((address_space(1))) void*)g,
      (__attribute__((address_space(3))) void*)l, 16, 0, 0);
}

// ---------------- elementwise cast f32 -> bf16 (4 elems/thread) ----------------
__global__ void cast_f32_bf16_k(const float* __restrict__ in, u16* __restrict__ out, int n4) {
  int i = blockIdx.x * 256 + threadIdx.x;
  if (i >= n4) return;
  float4 v = ((const float4*)in)[i];
  uint32_t lo = (uint32_t)f2b(v.x) | ((uint32_t)f2b(v.y) << 16);
  uint32_t hi = (uint32_t)f2b(v.z) | ((uint32_t)f2b(v.w) << 16);
  ((uint2*)out)[i] = make_uint2(lo, hi);
}

// ------- tiled transpose f32 (z,R,C) -> bf16 (z,C,R); 64x64 tile, vector IO -------
__global__ void transpose_f32_bf16_v(const float* __restrict__ in, u16* __restrict__ out,
                                     int R, int C) {
  __shared__ u16 t[64 * 72];
  int z = blockIdx.z;
  const float* pin = in + (size_t)z * R * C;
  u16* pout = out + (size_t)z * R * C;
  int c0 = blockIdx.x * 64, r0 = blockIdx.y * 64;
  int tid = threadIdx.x;
  int rr = tid >> 4, c4 = (tid & 15) * 4;
#pragma unroll
  for (int p = 0; p < 4; ++p) {
    int r = p * 16 + rr;
    float4 v = *(const float4*)&pin[(size_t)(r0 + r) * C + c0 + c4];
    t[(c4 + 0) * 72 + r] = f2b(v.x);
    t[(c4 + 1) * 72 + r] = f2b(v.y);
    t[(c4 + 2) * 72 + r] = f2b(v.z);
    t[(c4 + 3) * 72 + r] = f2b(v.w);
  }
  __syncthreads();
  int ct = tid >> 3, r8 = (tid & 7) * 8;
#pragma unroll
  for (int p = 0; p < 2; ++p) {
    int c = p * 32 + ct;
    uint2 lo = *(const uint2*)&t[c * 72 + r8];
    uint2 hi = *(const uint2*)&t[c * 72 + r8 + 4];
    *(uint4*)&pout[(size_t)(c0 + c) * R + r0 + r8] = make_uint4(lo.x, lo.y, hi.x, hi.y);
  }
}

// --- src prep: f32 (b,S,D) -> bf16 copy (b,S,D) + bf16 transpose (b,D,S); vector IO ---
__global__ void src_prep_v(const float* __restrict__ in, u16* __restrict__ outc,
                           u16* __restrict__ outT) {
  __shared__ u16 t[64 * 72];
  int z = blockIdx.z;
  const float* pin = in + (size_t)z * S_ * D_;
  u16* pc = outc + (size_t)z * S_ * D_;
  u16* pt = outT + (size_t)z * S_ * D_;
  int c0 = blockIdx.x * 64, r0 = blockIdx.y * 64;  // r over S, c over D
  int tid = threadIdx.x;
  int rr = tid >> 4, c4 = (tid & 15) * 4;
#pragma unroll
  for (int p = 0; p < 4; ++p) {
    int r = p * 16 + rr;
    float4 v = *(const float4*)&pin[(size_t)(r0 + r) * D_ + c0 + c4];
    u16 b0 = f2b(v.x), b1 = f2b(v.y), b2 = f2b(v.z), b3 = f2b(v.w);
    uint2 pk;
    pk.x = (uint32_t)b0 | ((uint32_t)b1 << 16);
    pk.y = (uint32_t)b2 | ((uint32_t)b3 << 16);
    *(uint2*)&pc[(size_t)(r0 + r) * D_ + c0 + c4] = pk;
    t[(c4 + 0) * 72 + r] = b0;
    t[(c4 + 1) * 72 + r] = b1;
    t[(c4 + 2) * 72 + r] = b2;
    t[(c4 + 3) * 72 + r] = b3;
  }
  __syncthreads();
  int ct = tid >> 3, r8 = (tid & 7) * 8;
#pragma unroll
  for (int p = 0; p < 2; ++p) {
    int c = p * 32 + ct;
    uint2 lo = *(const uint2*)&t[c * 72 + r8];
    uint2 hi = *(const uint2*)&t[c * 72 + r8 + 4];
    *(uint4*)&pt[(size_t)(c0 + c) * S_ + r0 + r8] = make_uint4(lo.x, lo.y, hi.x, hi.y);
  }
}

// ------- scale srcT (b,d,s) in place by 1/l[b*S+s]; 8 elems/thread -------
__global__ void scale_srcT_k(u16* __restrict__ srcT, const float* __restrict__ l) {
  size_t i = (size_t)blockIdx.x * 256 + threadIdx.x;  // group of 8 u16
  size_t e0 = i * 8;
  int s8 = (int)(e0 & (S_ - 1));
  int bb = (int)(e0 / ((size_t)D_ * S_));
  const float* lp = l + (size_t)bb * S_ + s8;
  float4 l0 = *(const float4*)lp;
  float4 l1 = *(const float4*)(lp + 4);
  uint4 raw = *(uint4*)&srcT[e0];
  uint32_t w[4] = {raw.x, raw.y, raw.z, raw.w};
  float li[8] = {l0.x, l0.y, l0.z, l0.w, l1.x, l1.y, l1.z, l1.w};
  uint32_t o[4];
#pragma unroll
  for (int k = 0; k < 4; ++k) {
    float a = b2f((u16)(w[k] & 0xffffu)) / li[2 * k];
    float b = b2f((u16)(w[k] >> 16)) / li[2 * k + 1];
    o[k] = (uint32_t)f2b(a) | ((uint32_t)f2b(b) << 16);
  }
  *(uint4*)&srcT[e0] = make_uint4(o[0], o[1], o[2], o[3]);
}

// =====================================================================
// 256x256-tile BT-GEMM, R11 = R9 (fragment-contiguous LDS, conflicts
// 5.2e5; vmcnt(6) 3-half-tile ledger; peeled tail — all verified) with
// reads REDISTRIBUTED to m201's per-phase pattern 12/4/8/4.
// Diagnosis (R9 postmortem): phase time = max(own-phase LDS drain,
// MFMA). R6-R9 front-loaded 16 reads/wave into ph1 (128 b128/CU ~1540
// cyc forced by lgkmcnt(0) before a 620-cyc MFMA) with 0-read phases
// wasted -> 1640 cyc/phase. m201 reads per phase only that phase's
// fragments: 12/4/8/4 -> balanced ~824 cyc/phase. R5 had this balance
// but conflicted reads; R6-R9 fixed conflicts but lost balance. R11
// combines both for the first time.
// Phase rota per K-tile (quadrants (0,0),(0,1),(1,1),(1,0)):
//  ph1: RD_A(h0) 8 + RD_B(b0) 4 -> MFMA(0,0)
//  ph2: RD_B(b1) 4              -> MFMA(0,1)   [av held]
//  ph3: RD_A(h1) 8              -> MFMA(1,1)   [bv held]
//  ph4: RD_B(b0) 4  (re-read)   -> MFMA(1,0)   [av held]
// Stage rota, fences, peel = R9 verbatim (1 half-tile/phase; vmcnt(6)
// at ph4/ph8 retiring exactly one K-tile; peel stages only Y.B_h0 and
// drains vmcnt(0) at ph4).
// WAR audit under new read timing: each region's reads drain at that
// phase's LGKM0, >= 1 barrier before its overwriting STG:
//  XA_h0 rd ph1/stg ph2; XB_h1 rd ph2/stg ph3; XA_h1 rd ph3/stg ph4;
//  XB_h0 rd ph1+ph4/stg ph5; YA_h0 rd ph5/stg ph6; YB_h1 rd ph6/stg
//  ph7; YA_h1 rd ph7/stg ph8; YB_h0 rd ph5+ph8/stg next-ph1.   All OK.
// modes: 0 tanh->bf16, 2 ->f32, 3 P=exp(C) -> transposed bf16 + row-sums.
// =====================================================================
__global__ __launch_bounds__(512, 2) void gemm256_k(
    const u16* __restrict__ A1, long lda1, long bsA1,
    const u16* __restrict__ B1, long ldb1, long bsB1,
    const u16* __restrict__ A2, long lda2, long bsA2,
    const u16* __restrict__ B2, long ldb2, long bsB2,
    void* __restrict__ Cv, long ldc, long bsC,
    int K, int Srows, int nTerms, int mode, float* __restrict__ lsum) {
  __shared__ __align__(16) u16 lds[65536];  // 128 KiB

  const int tid = threadIdx.x;
  const int w = tid >> 6, lane = tid & 63;
  const int wr = w >> 2, wc = w & 3;
  const int l15 = lane & 15, lhi4 = lane >> 4;

  // T1: bijective XCD-aware swizzle of the linear block id
  const int gx = gridDim.x;
  const int nwg = gx * (int)gridDim.y;
  int lid = blockIdx.y * gx + blockIdx.x;
  if ((nwg & 7) == 0) lid = (lid & 7) * (nwg >> 3) + (lid >> 3);
  const int bn = lid % gx, bm = lid / gx;
  const int n0 = bn * 256, m0 = bm * 256;
  const int b = m0 / Srows;
  const int s0 = m0 - b * Srows;

  const int ktiles = K >> 6;            // power of two (16 or 32)
  const int ktlog = __ffs(ktiles) - 1;
  const int ktmask = ktiles - 1;
  const int NT = nTerms * ktiles;       // total K-tiles (even, >= 4)

  const u16* gA1 = A1 + (size_t)bsA1 * b + (size_t)s0 * lda1;
  const u16* gB1 = B1 + (size_t)bsB1 * b + (size_t)n0 * ldb1;
  const u16* gA2 = (nTerms > 1) ? (A2 + (size_t)bsA2 * b + (size_t)s0 * lda2) : gA1;
  const u16* gB2 = (nTerms > 1) ? (B2 + (size_t)bsB2 * b + (size_t)n0 * ldb2) : gB1;

  // stage one half-tile = 16 fragment blocks (2 async16/wave).
  // A half h: s in {h*4..h*4+3} u {8+h*4..11+h*4}
  // B half h: s in {p*4 + h*2, p*4+h*2+1 : p=0..3}
  auto STG = [&](int tile, int isB, int half) {
    if (tile >= NT) return;
    const int term = tile >> ktlog;
    const int kt = (tile & ktmask) << 6;
    const u16* g = isB ? (term ? gB2 : gB1) : (term ? gA2 : gA1);
    const long ld = isB ? (term ? ldb2 : ldb1) : (term ? lda2 : lda1);
    u16* lb = lds + (tile & 1) * 32768 + isB * 16384;
#pragma unroll
    for (int is = 0; is < 2; ++is) {
      const int bi = is * 8 + w;
      int s, kk;
      if (isB) { s = (bi >> 2) * 4 + half * 2 + (bi & 1); kk = (bi >> 1) & 1; }
      else     { s = half * 4 + (bi & 3) + (bi >> 3) * 8; kk = (bi >> 2) & 1; }
      async16(g + (size_t)(s * 16 + l15) * ld + kt + kk * 32 + lhi4 * 8,
              lb + s * 1024 + kk * 512);
    }
  };

  f32x4 acc[8][4];
#pragma unroll
  for (int x = 0; x < 8; ++x)
#pragma unroll
    for (int y = 0; y < 4; ++y)
#pragma unroll
      for (int r = 0; r < 4; ++r) acc[x][y][r] = 0.0f;

  u16* bufXA = lds;            // even K-tiles
  u16* bufXB = lds + 16384;
  u16* bufYA = lds + 32768;    // odd K-tiles
  u16* bufYB = lds + 49152;

  const int lof = lane * 8;    // u16 offset of this lane's 16-B frag in a block

  short8 av[4][2], bv[2][2];

#define RD_A(bufA, mh)                                                         \
  _Pragma("unroll") for (int kk = 0; kk < 2; ++kk)                             \
  _Pragma("unroll") for (int fr = 0; fr < 4; ++fr)                             \
      av[fr][kk] =                                                             \
          *(const short8*)&(bufA)[(wr * 8 + (mh)*4 + fr) * 1024 + kk * 512 + lof];
#define RD_B(bufB, bp)                                                         \
  _Pragma("unroll") for (int kk = 0; kk < 2; ++kk)                             \
  _Pragma("unroll") for (int fc = 0; fc < 2; ++fc)                             \
      bv[fc][kk] =                                                             \
          *(const short8*)&(bufB)[(wc * 4 + (bp)*2 + fc) * 1024 + kk * 512 + lof];
#define BAR __builtin_amdgcn_s_barrier()
#define LGKM0 asm volatile("s_waitcnt lgkmcnt(0)")
#define VMC6 asm volatile("s_waitcnt vmcnt(6)" ::: "memory")
#define VMC0 asm volatile("s_waitcnt vmcnt(0)" ::: "memory")
#define MFMA16(mh, bp)                                                         \
  __builtin_amdgcn_s_setprio(1);                                               \
  _Pragma("unroll") for (int kk = 0; kk < 2; ++kk)                             \
  _Pragma("unroll") for (int fr = 0; fr < 4; ++fr)                             \
  _Pragma("unroll") for (int fc = 0; fc < 2; ++fc)                             \
      acc[(mh)*4 + fr][(bp)*2 + fc] = __builtin_amdgcn_mfma_f32_16x16x32_bf16( \
          av[fr][kk], bv[fc][kk], acc[(mh)*4 + fr][(bp)*2 + fc], 0, 0, 0);     \
  __builtin_amdgcn_s_setprio(0)

  // prologue: X0 all 4 halves + Y1 {A_h0, B_h1, A_h1} -> 14 loads/wave
  STG(0, 0, 0); STG(0, 1, 0); STG(0, 0, 1); STG(0, 1, 1);
  STG(1, 0, 0); STG(1, 1, 1); STG(1, 0, 1);
  VMC6;  // retires X0's 8; Y1's 6 stay in flight (steady invariant)
  BAR;

  const int niter = NT >> 1;
  for (int i = 0; i + 1 < niter; ++i) {
    const int u = 2 * i;
    // ph1: 12 reads
    RD_A(bufXA, 0); RD_B(bufXB, 0);
    STG(u + 1, 1, 0);                 // Y.B_h0
    BAR; LGKM0;
    MFMA16(0, 0);
    BAR;
    // ph2: 4 reads
    RD_B(bufXB, 1);
    STG(u + 2, 0, 0);                 // X'.A_h0 (region read ph1)
    BAR; LGKM0;
    MFMA16(0, 1);
    BAR;
    // ph3: 8 reads
    RD_A(bufXA, 1);
    STG(u + 2, 1, 1);                 // X'.B_h1 (region read ph2)
    BAR; LGKM0;
    MFMA16(1, 1);
    BAR;
    // ph4: 4 reads (B_h0 re-read)
    RD_B(bufXB, 0);
    STG(u + 2, 0, 1);                 // X'.A_h1 (region read ph3)
    BAR; LGKM0;
    MFMA16(1, 0);
    VMC6;                             // retires exactly Y's 4 half-tiles
    BAR;
    // ph5: 12 reads
    RD_A(bufYA, 0); RD_B(bufYB, 0);
    STG(u + 2, 1, 0);                 // X'.B_h0 (region read ph1+ph4)
    BAR; LGKM0;
    MFMA16(0, 0);
    BAR;
    // ph6: 4 reads
    RD_B(bufYB, 1);
    STG(u + 3, 0, 0);                 // Y'.A_h0 (region read ph5)
    BAR; LGKM0;
    MFMA16(0, 1);
    BAR;
    // ph7: 8 reads
    RD_A(bufYA, 1);
    STG(u + 3, 1, 1);                 // Y'.B_h1 (region read ph6)
    BAR; LGKM0;
    MFMA16(1, 1);
    BAR;
    // ph8: 4 reads (B_h0 re-read)
    RD_B(bufYB, 0);
    STG(u + 3, 0, 1);                 // Y'.A_h1 (region read ph7)
    BAR; LGKM0;
    MFMA16(1, 0);
    VMC6;                             // retires exactly X''s 4 half-tiles
    BAR;
  }

  // ---- peeled last iteration (X = NT-2, Y = NT-1): VMC0 full drain ----
  {
    // ph1
    RD_A(bufXA, 0); RD_B(bufXB, 0);
    STG(NT - 1, 1, 0);                // Y.B_h0 (last in-range stage)
    BAR; LGKM0;
    MFMA16(0, 0);
    BAR;
    // ph2
    RD_B(bufXB, 1);
    BAR; LGKM0;
    MFMA16(0, 1);
    BAR;
    // ph3
    RD_A(bufXA, 1);
    BAR; LGKM0;
    MFMA16(1, 1);
    BAR;
    // ph4
    RD_B(bufXB, 0);
    BAR; LGKM0;
    MFMA16(1, 0);
    VMC0;                             // 8 in flight -> 0: all Y landed
    BAR;
    // ph5
    RD_A(bufYA, 0); RD_B(bufYB, 0);
    BAR; LGKM0;
    MFMA16(0, 0);
    BAR;
    // ph6
    RD_B(bufYB, 1);
    BAR; LGKM0;
    MFMA16(0, 1);
    BAR;
    // ph7
    RD_A(bufYA, 1);
    BAR; LGKM0;
    MFMA16(1, 1);
    BAR;
    // ph8
    RD_B(bufYB, 0);
    BAR; LGKM0;
    MFMA16(1, 0);
    // nothing in flight; epilogue may reuse LDS after __syncthreads
  }

  // C/D layout (16x16): col = l&15, row = (l>>4)*4 + reg  [m89-verified]
  // global row = wr*128 + fr*16 + lhi4*4 + reg; col = wc*64 + fc*16 + l15
  if (mode == 3) {
#pragma unroll
    for (int fr = 0; fr < 8; ++fr)
#pragma unroll
      for (int fc = 0; fc < 4; ++fc)
#pragma unroll
        for (int r = 0; r < 4; ++r) acc[fr][fc][r] = __expf(acc[fr][fc][r]);
    // row sums over this block's 256 cols
    float* lrowp = lsum + (size_t)b * Srows + s0;
#pragma unroll
    for (int fr = 0; fr < 8; ++fr)
#pragma unroll
      for (int r = 0; r < 4; ++r) {
        float pv = acc[fr][0][r] + acc[fr][1][r] + acc[fr][2][r] + acc[fr][3][r];
        pv += __shfl_xor(pv, 1);
        pv += __shfl_xor(pv, 2);
        pv += __shfl_xor(pv, 4);
        pv += __shfl_xor(pv, 8);
        if (l15 == 0) {
          const int row = wr * 128 + fr * 16 + lhi4 * 4 + r;
          atomicAdd(&lrowp[row], pv);
        }
      }
    // transposed bf16 write via LDS reuse; two passes of 128 t-cols.
    u16* gP = (u16*)Cv + (size_t)bsC * b + (size_t)n0 * ldc + s0;
    __syncthreads();
#pragma unroll
    for (int p = 0; p < 2; ++p) {
      if ((wc >> 1) == p) {
#pragma unroll
        for (int fr = 0; fr < 8; ++fr)
#pragma unroll
          for (int fc = 0; fc < 4; ++fc) {
            const int tc = (wc & 1) * 64 + fc * 16 + l15;
            const int sl = wr * 128 + fr * 16 + lhi4 * 4;
            u16 p0 = f2b(acc[fr][fc][0]);
            u16 p1 = f2b(acc[fr][fc][1]);
            u16 p2 = f2b(acc[fr][fc][2]);
            u16 p3 = f2b(acc[fr][fc][3]);
            uint2 pk;
            pk.x = (uint32_t)p0 | ((uint32_t)p1 << 16);
            pk.y = (uint32_t)p2 | ((uint32_t)p3 << 16);
            *(uint2*)&lds[tc * 268 + sl] = pk;
          }
      }
      __syncthreads();
#pragma unroll
      for (int j = 0; j < 8; ++j) {
        const int idx = j * 512 + tid;
        const int tt = idx >> 5, s8 = (idx & 31) * 8;
        uint2 lo = *(const uint2*)&lds[tt * 268 + s8];
        uint2 h2 = *(const uint2*)&lds[tt * 268 + s8 + 4];
        *(uint4*)&gP[(size_t)(p * 128 + tt) * ldc + s8] =
            make_uint4(lo.x, lo.y, h2.x, h2.y);
      }
      __syncthreads();
    }
    return;
  }

  const size_t cb = (size_t)bsC * b + (size_t)s0 * ldc + n0;
  if (mode == 2) {
    float* C = (float*)Cv + cb;
#pragma unroll
    for (int fr = 0; fr < 8; ++fr)
#pragma unroll
      for (int fc = 0; fc < 4; ++fc) {
        const int col = wc * 64 + fc * 16 + l15;
#pragma unroll
        for (int r = 0; r < 4; ++r) {
          const int row = wr * 128 + fr * 16 + lhi4 * 4 + r;
          C[(size_t)row * ldc + col] = acc[fr][fc][r];
        }
      }
  } else {
    u16* C = (u16*)Cv + cb;
#pragma unroll
    for (int fr = 0; fr < 8; ++fr)
#pragma unroll
      for (int fc = 0; fc < 4; ++fc) {
        const int col = wc * 64 + fc * 16 + l15;
#pragma unroll
        for (int r = 0; r < 4; ++r) {
          const int row = wr * 128 + fr * 16 + lhi4 * 4 + r;
          float v = acc[fr][fc][r];
          if (mode == 0) v = tanh_fast(v);
          C[(size_t)row * ldc + col] = f2b(v);
        }
      }
  }
}

#undef RD_A
#undef RD_B
#undef BAR
#undef LGKM0
#undef VMC6
#undef VMC0
#undef MFMA16

extern "C" void kernel_launch(void* const* d_in, const int* in_sizes, int n_in,
                              void* d_out, int out_size, void* d_ws, size_t ws_size,
                              hipStream_t stream) {
  const float* src = (const float*)d_in[0];  // (B,S,D)
  const float* qry = (const float*)d_in[1];  // (B,Q,D)
  const float* ker = (const float*)d_in[2];  // (Q,T)
  const float* wk  = (const float*)d_in[3];  // (D,Q)
  const float* wq  = (const float*)d_in[4];  // (S,D)
  float* out = (float*)d_out;                // (B,T,D)
  u16* ws = (u16*)d_ws;

  // workspace layout (halfwords); ~240 MB
  u16* srcb  = ws;                                // (B,S,D) bf16
  u16* qryb  = srcb  + (size_t)B_ * S_ * D_;      // (B,Q,D) bf16
  u16* wqb   = qryb  + (size_t)B_ * Q_ * D_;      // (S,D) bf16
  u16* wkT   = wqb   + (size_t)S_ * D_;           // (Q,D) bf16
  u16* kerT  = wkT   + (size_t)D_ * Q_;           // (T,Q) bf16
  u16* srcT  = kerT  + (size_t)Q_ * T_;           // (B,D,S) bf16; scaled in place by 1/l
  u16* tanhT = srcT  + (size_t)B_ * D_ * S_;      // (B,S,Q) bf16
  u16* PT    = tanhT + (size_t)B_ * S_ * Q_;      // (B,T,S) bf16 = exp(sim)^T
  float* l   = (float*)(PT + (size_t)B_ * T_ * S_);  // (B*S) row sums

  dim3 tb(256);

  // prep
  cast_f32_bf16_k<<<(B_ * Q_ * D_) / 1024, 256, 0, stream>>>(qry, qryb, (B_ * Q_ * D_) / 4);
  cast_f32_bf16_k<<<(S_ * D_) / 1024, 256, 0, stream>>>(wq, wqb, (S_ * D_) / 4);
  transpose_f32_bf16_v<<<dim3(Q_ / 64, D_ / 64, 1), tb, 0, stream>>>(wk, wkT, D_, Q_);
  transpose_f32_bf16_v<<<dim3(T_ / 64, Q_ / 64, 1), tb, 0, stream>>>(ker, kerT, Q_, T_);
  src_prep_v<<<dim3(D_ / 64, S_ / 64, B_), tb, 0, stream>>>(src, srcb, srcT);
  hipMemsetAsync(l, 0, (size_t)B_ * S_ * sizeof(float), stream);

  // GEMM1: tanh(src@wk + wq@q_t) -> tanhT  (M=B*S, N=Q, K=D, 2 terms)
  gemm256_k<<<dim3(Q_ / 256, (B_ * S_) / 256), 512, 0, stream>>>(
      srcb, D_, (long)S_ * D_,
      wkT, D_, 0,
      wqb, D_, 0,
      qryb, D_, (long)Q_ * D_,
      tanhT, Q_, (long)S_ * Q_,
      D_, S_, 2, 0, nullptr);

  // GEMM2: P^T = exp(tanhT @ kernel)^T -> PT (B,T,S); row sums -> l
  gemm256_k<<<dim3(T_ / 256, (B_ * S_) / 256), 512, 0, stream>>>(
      tanhT, Q_, (long)S_ * Q_,
      kerT, Q_, 0,
      nullptr, 0, 0, nullptr, 0, 0,
      PT, S_, (long)T_ * S_,
      Q_, S_, 1, 3, l);

  // scale srcT by 1/l (in place)
  scale_srcT_k<<<(B_ * D_ * S_) / (256 * 8), 256, 0, stream>>>(srcT, l);

  // GEMM3: out[b] = PT[b] @ srcT_scaled[b]  (M=B*T, N=D, K=S), fp32 epilogue
  gemm256_k<<<dim3(D_ / 256, (B_ * T_) / 256), 512, 0, stream>>>(
      PT, S_, (long)T_ * S_,
      srcT, S_, (long)D_ * S_,
      nullptr, 0, 0, nullptr, 0, 0,
      out, D_, (long)T_ * D_,
      S_, T_, 1, 2, nullptr);
}